// Round 10
// baseline (453.694 us; speedup 1.0000x reference)
//
#include <hip/hip_runtime.h>
#include <hip/hip_bf16.h>

// Problem: B=16,S=64 -> BS=1024 sequences, L=128 tokens, D=512, F=256 filters
// per conv width Kw in {3,4,5}, V=30000.
// out[bs, c*256 + f] = relu(max_t (conv_c(x)[t,f]) + b_c[f]), fp32.
//
// R7:  16x16x32, 16 waves (2m x 8n): conv 363. R8-R12 (32x32): 390-417.
// R13: R7 + NT gather + bit-6 swizzle: conv 358, conflicts UNCHANGED
//      (5.033e7 = 4 cyc per ds_read_b128). Model (validated by R10-vs-R13):
//      LDS serves b128 per 32-lane half; conflict-free needs the half's 32
//      lanes on 32 DISTINCT 16B positions mod 512. 16 rows x 2 lk per half
//      under any single-field XOR -> 2 lanes/position -> +4 cyc. A-LDS =
//      64x16 = 1024 of the 1119 cyc/step: LDS-saturated, tax = 23%.
// R14: two-field swizzle g = ((q^(r&7))<<2) | (lk^((r&8)>>2)): row bits
//      reach BOTH granule sub-fields -> bijective per half on read (16 rows
//      x 2 lk -> 32 positions) and per row on write. r&7, r&8 both
//      mt-invariant -> addressing still base[mt] + ((q<<6)^E) + S,
//      2 VALU/step. Everything else identical to R13.

typedef __bf16 bf16x8 __attribute__((ext_vector_type(8)));
typedef float f32x4 __attribute__((ext_vector_type(4)));

#define ROWS 132                      // 128 real + 4 zero rows (K=5 window)
#define ROWB 512                      // bytes per row per half-D buffer
#define BUF_BYTES (ROWS * ROWB)       // 67584
#define RED_OFF (2 * BUF_BYTES)       // 135168
#define LDS_TOTAL (RED_OFF + 2048)    // 137216 (red: 2 x 256 f32)

// -------- pack_w: MFMA-fragment-ordered chunks (16x16, as R5/R7) ------------
// Chunk g = (c, kq, n16), 1024 B = 64 lanes x 16 B. Element (lane, j):
//   f = n16*16 + (lane&15), k = kq*32 + (lane>>4)*8 + j, tap = k>>9, d = k&511
//   src = w_c[f][d][tap]  (layout [F][D][Kw]).
__global__ void pack_w_kernel(const float* __restrict__ w3,
                              const float* __restrict__ w4,
                              const float* __restrict__ w5,
                              __bf16* __restrict__ wq) {
    const int t    = blockIdx.x * 256 + threadIdx.x;  // 0..196607
    const int g    = t >> 6;                          // chunk 0..3071
    const int lane = t & 63;
    int rel, Kw; const float* w;
    if (g < 768)       { rel = g;        Kw = 3; w = w3; }
    else if (g < 1792) { rel = g - 768;  Kw = 4; w = w4; }
    else               { rel = g - 1792; Kw = 5; w = w5; }
    const int kq  = rel >> 4;
    const int n16 = rel & 15;
    const int f   = n16 * 16 + (lane & 15);
    const int k0  = kq * 32 + (lane >> 4) * 8;        // frag never straddles tap
    const int tap = k0 >> 9;
    const int d0  = k0 & 511;
    const float* src = w + ((size_t)f * 512 + d0) * Kw + tap;
    bf16x8 o;
#pragma unroll
    for (int j = 0; j < 8; ++j) o[j] = (__bf16)src[j * Kw];
    *(bf16x8*)(wq + (size_t)t * 8) = o;
}

// ---------------- persistent fused gather + conv GEMM -----------------------
__global__ __launch_bounds__(1024, 4) void conv_gemm_kernel(
        const int* __restrict__ text,
        const float* __restrict__ embed,
        const __bf16* __restrict__ wq,
        const float* __restrict__ b3,
        const float* __restrict__ b4,
        const float* __restrict__ b5,
        float* __restrict__ out) {
    extern __shared__ char lds[];
    float* const red = (float*)(lds + RED_OFF);

    const int tid  = threadIdx.x;
    const int lane = tid & 63;
    const int wave = tid >> 6;         // 0..15
    const int wm   = wave & 1;         // m-half 0..1 (64 rows each)
    const int wn   = wave >> 1;        // n-slice 0..7 (32 cols each)
    const int lm = lane & 15, lk = lane >> 4;
    const int sr = tid >> 5;           // staging row-in-pass 0..31
    const int sc = tid & 31;           // staging col (chunk) 0..31

    // ---- gather staging: 2 passes (64 rows) per pair, 16 B dst/thread ----
    f32x4 G[4];
    auto issuePair = [&](int nbs, int h, int p0) {
#pragma unroll
        for (int p = 0; p < 2; ++p) {
            const int r = (p0 + p) * 32 + sr;
            const int tok = text[nbs * 128 + r];
            const f32x4* src = (const f32x4*)
                (embed + (size_t)tok * 512 + h * 256 + sc * 8);
            G[p * 2]     = __builtin_nontemporal_load(src);
            G[p * 2 + 1] = __builtin_nontemporal_load(src + 1);
        }
    };
    // chunk c=sc holds elements 8c..8c+7 = (q=sc>>2, lk=sc&3); place at
    // granule ((q^(r&7))<<2) | (lk^((r&8)>>2)).
    auto writePair = [&](char* bufp, int p0) {
#pragma unroll
        for (int p = 0; p < 2; ++p) {
            const int r = (p0 + p) * 32 + sr;
            const f32x4 v0 = G[p * 2], v1 = G[p * 2 + 1];
            bf16x8 o;
            o[0] = (__bf16)v0.x; o[1] = (__bf16)v0.y;
            o[2] = (__bf16)v0.z; o[3] = (__bf16)v0.w;
            o[4] = (__bf16)v1.x; o[5] = (__bf16)v1.y;
            o[6] = (__bf16)v1.z; o[7] = (__bf16)v1.w;
            const int g = (((sc >> 2) ^ (r & 7)) << 2)
                        | ((sc & 3) ^ ((r & 8) >> 2));
            *(bf16x8*)(bufp + r * ROWB + (g << 4)) = o;
        }
    };

    f32x4 acc[4][2];
    bf16x8 B4[4][2];
    const __bf16* bp = wq;             // set per conv

    auto loadB = [&](bf16x8* d, int kb) {
        const __bf16* p = bp + (size_t)kb * 8192;
        d[0] = *(const bf16x8*)(p);
        d[1] = *(const bf16x8*)(p + 512);
    };

    // One d-half phase: KW taps x 8 kq-steps, barrier-free.
    auto runPhase = [&](const char* bufp, int KW, int h) {
        const int kh = h * 8;
        const int maxkq = (KW - 1) * 16 + kh + 7;
        loadB(B4[0], kh);     loadB(B4[1], kh + 1);
        loadB(B4[2], kh + 2); loadB(B4[3], kh + 3);
        for (int tap = 0; tap < KW; ++tap) {
            // A addr: base[mt] + ((q<<6) ^ E) ; E,S per-tap consts (mt-inv)
            const int E = ((lm + tap) & 7) << 6;
            const int S = (lk ^ (((lm + tap) & 8) >> 2)) << 4;
            int base[4];
#pragma unroll
            for (int mt = 0; mt < 4; ++mt)
                base[mt] = (wm * 64 + mt * 16 + lm + tap) * ROWB + S;
            const int kqt = tap * 16 + kh;
#pragma unroll
            for (int q = 0; q < 8; ++q) {
                bf16x8 a[4];
                const int off = (q << 6) ^ E;
#pragma unroll
                for (int mt = 0; mt < 4; ++mt)
                    a[mt] = *(const bf16x8*)(bufp + base[mt] + off);
                __builtin_amdgcn_s_setprio(1);
#pragma unroll
                for (int nt = 0; nt < 2; ++nt)
#pragma unroll
                    for (int mt = 0; mt < 4; ++mt)
                        acc[mt][nt] = __builtin_amdgcn_mfma_f32_16x16x32_bf16(
                            a[mt], B4[q & 3][nt], acc[mt][nt], 0, 0, 0);
                __builtin_amdgcn_s_setprio(0);
                // B prefetch for step q+4 (ring slot q&3); clamp = dead dup
                int kqn = kqt + ((q < 4) ? (q + 4) : (q + 12));
                kqn = (kqn <= maxkq) ? kqn : maxkq;
                loadB(B4[q & 3], kqn);
            }
        }
    };

    // ---- prolog: stage bs(i=0) both halves + zero pad rows (once) ----
    const int bsbase = blockIdx.x * 4;
    issuePair(bsbase, 0, 0); writePair(lds, 0);
    issuePair(bsbase, 0, 2); writePair(lds, 2);
    issuePair(bsbase, 1, 0); writePair(lds + BUF_BYTES, 0);
    issuePair(bsbase, 1, 2); writePair(lds + BUF_BYTES, 2);
    if (tid < 128) {                   // rows 128..131: zeros, any bijective
        const int r = 128 + sr;        //   placement covers the row
        const int off = r * ROWB + sc * 16;
        bf16x8 z = {};
        *(bf16x8*)(lds + off) = z;
        *(bf16x8*)(lds + BUF_BYTES + off) = z;
    }
    __syncthreads();

#pragma unroll 1
    for (int i = 0; i < 4; ++i) {
        const int bs  = bsbase + i;
        const int nbs = bs + 1;
        const bool stg = (i < 3);
#pragma unroll 1
        for (int c = 0; c < 3; ++c) {
            const int KW = 3 + c;
            bp = wq + ((c == 0) ? 0 : (c == 1) ? 393216 : 917504)
                    + (size_t)wn * 1024 + (size_t)lane * 8;
#pragma unroll
            for (int mt = 0; mt < 4; ++mt)
#pragma unroll
                for (int nt = 0; nt < 2; ++nt)
                    acc[mt][nt] = (f32x4){0.f, 0.f, 0.f, 0.f};

            const bool lastc = stg && (c == 2);
            if (lastc) issuePair(nbs, 0, 0);   // h0 rows 0..63: hide under h0
            runPhase(lds, KW, 0);
            if (lastc) {
                __syncthreads();               // all buf0 reads done
                writePair(lds, 0);
                issuePair(nbs, 0, 2);          // short stall (serial)
                writePair(lds, 2);
                issuePair(nbs, 1, 0);          // hide under h1
            }
            runPhase(lds + BUF_BYTES, KW, 1);

            // ---- epilogue conv c: masked max, cross-lane, cross-wave ----
            const int Tv = 126 - c;            // 126/125/124 valid positions
            float cmax[2];
#pragma unroll
            for (int nt = 0; nt < 2; ++nt) {
                float mx = -3.0e38f;
#pragma unroll
                for (int mt = 0; mt < 4; ++mt) {
                    const int mb = wm * 64 + mt * 16 + lk * 4;
#pragma unroll
                    for (int r = 0; r < 4; ++r)
                        if (mb + r < Tv) mx = fmaxf(mx, acc[mt][nt][r]);
                }
                mx = fmaxf(mx, __shfl_xor(mx, 16, 64));
                mx = fmaxf(mx, __shfl_xor(mx, 32, 64));
                cmax[nt] = mx;
            }
            __syncthreads();                   // buf1 reads + prev red done
            if (lastc) {
                writePair(lds + BUF_BYTES, 0);
                issuePair(nbs, 1, 2);          // short stall (serial)
                writePair(lds + BUF_BYTES, 2);
            }
            if (lk == 0) {
#pragma unroll
                for (int nt = 0; nt < 2; ++nt)
                    red[wm * 256 + wn * 32 + nt * 16 + lm] = cmax[nt];
            }
            __syncthreads();
            if (tid < 256) {
                const float* bias = (c == 0) ? b3 : (c == 1) ? b4 : b5;
                const float v = fmaxf(red[tid], red[256 + tid]) + bias[tid];
                out[(size_t)bs * 768 + c * 256 + tid] = fmaxf(v, 0.f);
            }
        }
    }
}

extern "C" void kernel_launch(void* const* d_in, const int* in_sizes, int n_in,
                              void* d_out, int out_size, void* d_ws, size_t ws_size,
                              hipStream_t stream) {
    const int*   text  = (const int*)d_in[0];
    const float* embed = (const float*)d_in[1];
    const float* w3    = (const float*)d_in[2];
    const float* b3    = (const float*)d_in[3];
    const float* w4    = (const float*)d_in[4];
    const float* b4    = (const float*)d_in[5];
    const float* w5    = (const float*)d_in[6];
    const float* b5    = (const float*)d_in[7];
    float* out = (float*)d_out;

    __bf16* wq = (__bf16*)d_ws;                 // 1572864 bf16 = 3.1 MB

    (void)hipFuncSetAttribute((const void*)conv_gemm_kernel,
                              hipFuncAttributeMaxDynamicSharedMemorySize,
                              LDS_TOTAL);

    pack_w_kernel<<<768, 256, 0, stream>>>(w3, w4, w5, wq);
    conv_gemm_kernel<<<256, 1024, LDS_TOTAL, stream>>>(text, embed, wq,
                                                       b3, b4, b5, out);
}